// Round 10
// baseline (42.438 us; speedup 1.0000x reference)
//
#include <hip/hip_runtime.h>

typedef float v4f __attribute__((ext_vector_type(4)));

#define NATOM 128
#define FEAT 128
#define FILT 128
#define BATCH 8

// Kernel 1: s-GEMM, 4 rows per block (256 blocks x 512 threads).
// thread = (rh, which, k): rh picks row-pair {0,1}/{2,3}; per-thread shape is
// the PROVEN R7 form (2 scalar accs, unroll 4, ~40 VGPR). Both rh-groups
// stream the same W columns -> L1/L2 merge, W L2 traffic 64 -> 32 MB.
__global__ __launch_bounds__(512) void s_gemm_kernel(
    const float* __restrict__ sf, const float* __restrict__ W,
    const float* __restrict__ bias, float* __restrict__ s1,
    float* __restrict__ s2) {
  const int r0 = blockIdx.x * 4;
  const int tid = threadIdx.x;
  const int k = tid & (FILT - 1);
  const int which = (tid >> 7) & 1;  // 0 -> s1, 1 -> s2
  const int rh = tid >> 8;           // row pair 0/1

  __shared__ float sfrow[4][FEAT];
  sfrow[tid >> 7][tid & 127] = sf[(r0 + (tid >> 7)) * FEAT + (tid & 127)];
  __syncthreads();

  const float* Wcol = W + which * FEAT * FILT + k;
  const int ra = 2 * rh, rb = 2 * rh + 1;
  float a0 = 0.f, a1 = 0.f;
#pragma unroll 4
  for (int f4 = 0; f4 < FEAT; f4 += 4) {
    const v4f sv0 = *reinterpret_cast<const v4f*>(&sfrow[ra][f4]);
    const v4f sv1 = *reinterpret_cast<const v4f*>(&sfrow[rb][f4]);
#pragma unroll
    for (int fi = 0; fi < 4; ++fi) {
      const float w = Wcol[(f4 + fi) * FILT];
      a0 = fmaf(sv0[fi], w, a0);
      a1 = fmaf(sv1[fi], w, a1);
    }
  }

  const float bb = which ? 0.f : bias[k];
  float* dst = (which ? s2 : s1) + (r0 + ra) * FILT + k;
  dst[0] = a0 + bb;
  dst[FILT] = a1 + bb;
}

// Kernel 2 (R7 exact form — at the 6.29 TB/s mixed-stream roofline):
// out[b,i,j,c,k] = (s1[b,i,k] + s2[b,j,k]) * dist[b,i,j,c]
// 2048 blocks (b,i,j-half), 256 threads = 8 j-lanes x 32 k-quads, direct
// in-loop dist loads, plain float4 stores, full unroll.
__global__ __launch_bounds__(256) void expand_kernel(
    const float* __restrict__ s1, const float* __restrict__ s2,
    const float* __restrict__ dist, float* __restrict__ out) {
  const int blk = blockIdx.x;
  const int bi = blk >> 1;         // b*N + i
  const int jh = blk & 1;          // which half of j
  const int b = bi >> 7;
  const int tid = threadIdx.x;
  const int kq = (tid & 31) << 2;  // k offset: 0..124 step 4
  const int jl = tid >> 5;         // 0..7

  const v4f s1v = *reinterpret_cast<const v4f*>(s1 + bi * FILT + kq);
  const float* s2base = s2 + ((size_t)(b << 7) + jh * 64) * FILT;
  const float* dbase = dist + ((size_t)bi * NATOM + jh * 64) * 3;
  float* obase = out + ((size_t)bi * NATOM + jh * 64) * 3 * FILT;

#pragma unroll
  for (int j0 = 0; j0 < 64; j0 += 8) {
    const int jloc = j0 + jl;
    const v4f s2v = *reinterpret_cast<const v4f*>(s2base + jloc * FILT + kq);
    const float d0 = dbase[jloc * 3 + 0];
    const float d1 = dbase[jloc * 3 + 1];
    const float d2 = dbase[jloc * 3 + 2];
    const v4f p = s1v + s2v;
    float* o = obase + (size_t)jloc * 3 * FILT + kq;
    *reinterpret_cast<v4f*>(o) = p * d0;
    *reinterpret_cast<v4f*>(o + FILT) = p * d1;
    *reinterpret_cast<v4f*>(o + 2 * FILT) = p * d2;
  }
}

extern "C" void kernel_launch(void* const* d_in, const int* in_sizes, int n_in,
                              void* d_out, int out_size, void* d_ws, size_t ws_size,
                              hipStream_t stream) {
  const float* sf   = (const float*)d_in[0];  // (8,128,128)
  const float* dist = (const float*)d_in[1];  // (8,128,128,3)
  const float* W    = (const float*)d_in[2];  // (256,128)
  const float* bias = (const float*)d_in[3];  // (1,128)
  float* out = (float*)d_out;                 // (8,128,128,3,128)

  float* s1 = (float*)d_ws;  // 1024*128 f32
  float* s2 = s1 + BATCH * NATOM * FILT;

  s_gemm_kernel<<<BATCH * NATOM / 4, 512, 0, stream>>>(sf, W, bias, s1, s2);
  expand_kernel<<<BATCH * NATOM * 2, 256, 0, stream>>>(s1, s2, dist, out);
}

// Round 11
// 40.904 us; speedup vs baseline: 1.0375x; 1.0375x over previous
//
#include <hip/hip_runtime.h>

typedef float v4f __attribute__((ext_vector_type(4)));

#define NATOM 128
#define FEAT 128
#define FILT 128
#define BATCH 8

// Kernel 1 (R7 form — best measured): s-GEMM, 2 rows per block, 512 blocks
// x 256 threads. thread = (which, k); each W element feeds 2 register
// accumulators; sf rows staged in LDS; unroll 4 keeps VGPRs modest.
// R4 (4-row, full unroll) and R10 (512-thread, 4-row) both regressed.
__global__ __launch_bounds__(256) void s_gemm_kernel(
    const float* __restrict__ sf, const float* __restrict__ W,
    const float* __restrict__ bias, float* __restrict__ s1,
    float* __restrict__ s2) {
  const int r0 = blockIdx.x * 2;
  const int tid = threadIdx.x;
  const int k = tid & (FILT - 1);
  const int which = tid >> 7;  // 0 -> s1, 1 -> s2

  __shared__ float sfrow[2][FEAT];
  sfrow[tid >> 7][tid & 127] = sf[(r0 + (tid >> 7)) * FEAT + (tid & 127)];
  __syncthreads();

  const float* Wcol = W + which * FEAT * FILT + k;
  float a0 = 0.f, a1 = 0.f;
#pragma unroll 4
  for (int f4 = 0; f4 < FEAT; f4 += 4) {
    const v4f sv0 = *reinterpret_cast<const v4f*>(&sfrow[0][f4]);
    const v4f sv1 = *reinterpret_cast<const v4f*>(&sfrow[1][f4]);
#pragma unroll
    for (int fi = 0; fi < 4; ++fi) {
      const float w = Wcol[(f4 + fi) * FILT];
      a0 = fmaf(sv0[fi], w, a0);
      a1 = fmaf(sv1[fi], w, a1);
    }
  }

  const float bb = which ? 0.f : bias[k];
  float* dst = (which ? s2 : s1) + r0 * FILT + k;
  dst[0] = a0 + bb;
  dst[FILT] = a1 + bb;
}

// Kernel 2 (R7 exact form — within ~1% of the 6.29 TB/s mixed-stream
// roofline: 201 MB writes + 25 MB dist reads + 8 MB s-traffic / 6.29 TB/s
// = 37.3 us floor, measured ~37.7 us):
// out[b,i,j,c,k] = (s1[b,i,k] + s2[b,j,k]) * dist[b,i,j,c]
// 2048 blocks (b,i,j-half), 256 threads = 8 j-lanes x 32 k-quads, direct
// in-loop dist loads, plain float4 stores, full unroll. Exonerated (null at
// +-1us): NT stores (worse), LDS dist staging, i-tiling x4, store-contiguity
// remap, preload+sched_barrier phase split, L2 read contention.
__global__ __launch_bounds__(256) void expand_kernel(
    const float* __restrict__ s1, const float* __restrict__ s2,
    const float* __restrict__ dist, float* __restrict__ out) {
  const int blk = blockIdx.x;
  const int bi = blk >> 1;         // b*N + i
  const int jh = blk & 1;          // which half of j
  const int b = bi >> 7;
  const int tid = threadIdx.x;
  const int kq = (tid & 31) << 2;  // k offset: 0..124 step 4
  const int jl = tid >> 5;         // 0..7

  const v4f s1v = *reinterpret_cast<const v4f*>(s1 + bi * FILT + kq);
  const float* s2base = s2 + ((size_t)(b << 7) + jh * 64) * FILT;
  const float* dbase = dist + ((size_t)bi * NATOM + jh * 64) * 3;
  float* obase = out + ((size_t)bi * NATOM + jh * 64) * 3 * FILT;

#pragma unroll
  for (int j0 = 0; j0 < 64; j0 += 8) {
    const int jloc = j0 + jl;
    const v4f s2v = *reinterpret_cast<const v4f*>(s2base + jloc * FILT + kq);
    const float d0 = dbase[jloc * 3 + 0];
    const float d1 = dbase[jloc * 3 + 1];
    const float d2 = dbase[jloc * 3 + 2];
    const v4f p = s1v + s2v;
    float* o = obase + (size_t)jloc * 3 * FILT + kq;
    *reinterpret_cast<v4f*>(o) = p * d0;
    *reinterpret_cast<v4f*>(o + FILT) = p * d1;
    *reinterpret_cast<v4f*>(o + 2 * FILT) = p * d2;
  }
}

extern "C" void kernel_launch(void* const* d_in, const int* in_sizes, int n_in,
                              void* d_out, int out_size, void* d_ws, size_t ws_size,
                              hipStream_t stream) {
  const float* sf   = (const float*)d_in[0];  // (8,128,128)
  const float* dist = (const float*)d_in[1];  // (8,128,128,3)
  const float* W    = (const float*)d_in[2];  // (256,128)
  const float* bias = (const float*)d_in[3];  // (1,128)
  float* out = (float*)d_out;                 // (8,128,128,3,128)

  float* s1 = (float*)d_ws;  // 1024*128 f32
  float* s2 = s1 + BATCH * NATOM * FILT;

  s_gemm_kernel<<<BATCH * NATOM / 2, 256, 0, stream>>>(sf, W, bias, s1, s2);
  expand_kernel<<<BATCH * NATOM * 2, 256, 0, stream>>>(s1, s2, dist, out);
}